// Round 1
// baseline (633.603 us; speedup 1.0000x reference)
//
#include <hip/hip_runtime.h>

typedef unsigned short u16;
typedef __attribute__((ext_vector_type(4))) u16 u16x4;
typedef __attribute__((ext_vector_type(8))) u16 u16x8;
typedef __attribute__((ext_vector_type(8))) short s16x8;   // 8 x bf16 (4 VGPRs)
typedef __attribute__((ext_vector_type(4))) float f32x4;

#define B_  4
#define C_  512
#define CI_ 256
#define HW_ 4096

static __device__ __forceinline__ u16 f2bf(float f) {
  unsigned u = __float_as_uint(f);
  return (u16)((u + 0x7FFFu + ((u >> 16) & 1u)) >> 16);   // RNE
}

static __device__ __forceinline__ f32x4 mfma16(s16x8 a, s16x8 b, f32x4 c) {
  return __builtin_amdgcn_mfma_f32_16x16x32_bf16(a, b, c, 0, 0, 0);
}

// ---------------------------------------------------------------------------
// K1: projections.  per (proj p, batch b): out = w(256x512) @ x_b(512x4096) + bias
//   p==0 (g)      -> g_s   (B, Ci, HW)  channel-major
//   p==1 (theta)  -> thetaT(B, HW, Ci)  token-major (transposed store via LDS)
//   p==2 (phi)    -> phiT  (B, HW, Ci)
// block: 256 thr (4 waves, 2x2), tile 64x64, K-step 32
// ---------------------------------------------------------------------------
__global__ __launch_bounds__(256) void k1_proj(
    const float* __restrict__ x,
    const float* __restrict__ wg, const float* __restrict__ bg,
    const float* __restrict__ wt, const float* __restrict__ bt,
    const float* __restrict__ wp, const float* __restrict__ bp,
    u16* __restrict__ g_s, u16* __restrict__ thetaT, u16* __restrict__ phiT)
{
  const int tid = threadIdx.x;
  const int lane = tid & 63, wid = tid >> 6;
  const int wm = wid >> 1, wn = wid & 1;
  const int l15 = lane & 15, g4 = lane >> 4;
  const int n0 = blockIdx.x * 64;
  const int m0 = blockIdx.y * 64;
  const int p = blockIdx.z >> 2, b = blockIdx.z & 3;
  const float* w    = (p == 0) ? wg : (p == 1) ? wt : wp;
  const float* bias = (p == 0) ? bg : (p == 1) ? bt : bp;
  const float* xb = x + (size_t)b * C_ * HW_;

  __shared__ u16 lds_x[32][76];   // [k][n] bf16, padded
  __shared__ u16 lds_t[64][72];   // epilogue transpose staging

  f32x4 acc[2][2] = {};

  for (int kk = 0; kk < C_; kk += 32) {
    __syncthreads();
#pragma unroll
    for (int i = 0; i < 2; ++i) {
      int idx = tid + i * 256;                  // 0..511 float4s
      int kr = idx >> 4, nc = (idx & 15) << 2;
      float4 v = *reinterpret_cast<const float4*>(&xb[(size_t)(kk + kr) * HW_ + n0 + nc]);
      u16x4 h; h[0] = f2bf(v.x); h[1] = f2bf(v.y); h[2] = f2bf(v.z); h[3] = f2bf(v.w);
      *reinterpret_cast<u16x4*>(&lds_x[kr][nc]) = h;
    }
    __syncthreads();

    s16x8 afr[2], bfr[2];
#pragma unroll
    for (int mf = 0; mf < 2; ++mf) {
      int row = m0 + wm * 32 + mf * 16 + l15;
      const float4* w4 = reinterpret_cast<const float4*>(&w[(size_t)row * C_ + kk + g4 * 8]);
      float4 v0 = w4[0], v1 = w4[1];
      s16x8 a;
      a[0] = (short)f2bf(v0.x); a[1] = (short)f2bf(v0.y);
      a[2] = (short)f2bf(v0.z); a[3] = (short)f2bf(v0.w);
      a[4] = (short)f2bf(v1.x); a[5] = (short)f2bf(v1.y);
      a[6] = (short)f2bf(v1.z); a[7] = (short)f2bf(v1.w);
      afr[mf] = a;
    }
#pragma unroll
    for (int nf = 0; nf < 2; ++nf) {
      int col = wn * 32 + nf * 16 + l15;
      s16x8 bb;
#pragma unroll
      for (int j = 0; j < 8; ++j) bb[j] = (short)lds_x[g4 * 8 + j][col];
      bfr[nf] = bb;
    }
#pragma unroll
    for (int mf = 0; mf < 2; ++mf)
#pragma unroll
      for (int nf = 0; nf < 2; ++nf)
        acc[mf][nf] = mfma16(afr[mf], bfr[nf], acc[mf][nf]);
  }

#pragma unroll
  for (int mf = 0; mf < 2; ++mf)
#pragma unroll
    for (int r = 0; r < 4; ++r) {
      float bv = bias[m0 + wm * 32 + mf * 16 + g4 * 4 + r];
      acc[mf][0][r] += bv; acc[mf][1][r] += bv;
    }

  if (p == 0) {
#pragma unroll
    for (int mf = 0; mf < 2; ++mf)
#pragma unroll
      for (int nf = 0; nf < 2; ++nf)
#pragma unroll
        for (int r = 0; r < 4; ++r) {
          int row = m0 + wm * 32 + mf * 16 + g4 * 4 + r;
          int col = n0 + wn * 32 + nf * 16 + l15;
          g_s[((size_t)b * CI_ + row) * HW_ + col] = f2bf(acc[mf][nf][r]);
        }
  } else {
#pragma unroll
    for (int mf = 0; mf < 2; ++mf)
#pragma unroll
      for (int nf = 0; nf < 2; ++nf)
#pragma unroll
        for (int r = 0; r < 4; ++r)
          lds_t[wm * 32 + mf * 16 + g4 * 4 + r][wn * 32 + nf * 16 + l15] = f2bf(acc[mf][nf][r]);
    __syncthreads();
    u16* outp = (p == 1) ? thetaT : phiT;
    int nl = tid >> 2, cs = (tid & 3) << 4;
    u16x8 v0, v1;
#pragma unroll
    for (int i = 0; i < 8; ++i) { v0[i] = lds_t[cs + i][nl]; v1[i] = lds_t[cs + 8 + i][nl]; }
    size_t dst = ((size_t)b * HW_ + n0 + nl) * CI_ + m0 + cs;
    *reinterpret_cast<u16x8*>(&outp[dst])     = v0;
    *reinterpret_cast<u16x8*>(&outp[dst + 8]) = v1;
  }
}

// ---------------------------------------------------------------------------
// K2: pass A — L[n] = sum_m exp(s[n,m]).  S^T tiles: rows m, cols n.
// block: 4 waves, each wave a 16-row m-slice, n-tile = 32 cols; m-range 512.
// ---------------------------------------------------------------------------
__global__ __launch_bounds__(256) void k2_lse(
    const u16* __restrict__ thetaT, const u16* __restrict__ phiT,
    float* __restrict__ Lpart)
{
  const int tid = threadIdx.x;
  const int lane = tid & 63, w = tid >> 6;
  const int l15 = lane & 15, g4 = lane >> 4;
  const int n0 = blockIdx.x * 32;
  const int ms = blockIdx.y;
  const int b  = blockIdx.z;
  const u16* thb = thetaT + (size_t)b * HW_ * CI_;
  const u16* phb = phiT   + (size_t)b * HW_ * CI_;

  float psum[2] = {0.f, 0.f};
  for (int it = 0; it < 8; ++it) {
    int mbase = ms * 512 + it * 64 + w * 16;
    f32x4 acc[2] = {};
#pragma unroll
    for (int c = 0; c < CI_; c += 32) {
      s16x8 a = *reinterpret_cast<const s16x8*>(&phb[(size_t)(mbase + l15) * CI_ + c + g4 * 8]);
#pragma unroll
      for (int nf = 0; nf < 2; ++nf) {
        s16x8 bb = *reinterpret_cast<const s16x8*>(&thb[(size_t)(n0 + nf * 16 + l15) * CI_ + c + g4 * 8]);
        acc[nf] = mfma16(a, bb, acc[nf]);
      }
    }
#pragma unroll
    for (int nf = 0; nf < 2; ++nf)
#pragma unroll
      for (int r = 0; r < 4; ++r)
        psum[nf] += __expf(acc[nf][r] * 0.0625f);
  }
#pragma unroll
  for (int nf = 0; nf < 2; ++nf) {
    psum[nf] += __shfl_xor(psum[nf], 16);
    psum[nf] += __shfl_xor(psum[nf], 32);
  }
  __shared__ float lds_r[4][32];
  if (lane < 16) { lds_r[w][lane] = psum[0]; lds_r[w][16 + lane] = psum[1]; }
  __syncthreads();
  if (tid < 32) {
    float s = lds_r[0][tid] + lds_r[1][tid] + lds_r[2][tid] + lds_r[3][tid];
    Lpart[((size_t)ms * 4 + b) * HW_ + n0 + tid] = s;
  }
}

__global__ void k2b_lred(const float* __restrict__ Lpart, float* __restrict__ invL)
{
  int i = blockIdx.x * 256 + threadIdx.x;   // 0..16383 = b*4096+n
  float s = 0.f;
#pragma unroll
  for (int m = 0; m < 8; ++m)
    s += Lpart[((size_t)m * 4 + (i >> 12)) * HW_ + (i & 4095)];
  invL[i] = 1.0f / s;
}

// ---------------------------------------------------------------------------
// K3: pass B — y[n,c] = (1/L[n]) * sum_m exp(s[n,m]) * g[c,m]
// block: n-tile 32 rows; 4 waves: wave w computes m-slice 16 of S^T, then PV
// over its own c-range 64 (c0=64w).  P exchanged through LDS.
// ---------------------------------------------------------------------------
__global__ __launch_bounds__(256) void k3_attn(
    const u16* __restrict__ thetaT, const u16* __restrict__ phiT,
    const u16* __restrict__ g_s, const float* __restrict__ invL,
    u16* __restrict__ y)
{
  const int tid = threadIdx.x;
  const int lane = tid & 63, w = tid >> 6;
  const int l15 = lane & 15, g4 = lane >> 4;
  const int n0 = blockIdx.x * 32;
  const int b  = blockIdx.y;
  const u16* thb = thetaT + (size_t)b * HW_ * CI_;
  const u16* phb = phiT   + (size_t)b * HW_ * CI_;
  const u16* gsb = g_s    + (size_t)b * CI_ * HW_;

  __shared__ u16 lds_p[32][72];   // [n][m] bf16, padded (row stride 144B)

  f32x4 oacc[2][4] = {};
  const int c0 = w * 64;

  for (int it = 0; it < 64; ++it) {
    int mbase = it * 64 + w * 16;
    f32x4 acc[2] = {};
#pragma unroll
    for (int c = 0; c < CI_; c += 32) {
      s16x8 a = *reinterpret_cast<const s16x8*>(&phb[(size_t)(mbase + l15) * CI_ + c + g4 * 8]);
#pragma unroll
      for (int nf = 0; nf < 2; ++nf) {
        s16x8 bb = *reinterpret_cast<const s16x8*>(&thb[(size_t)(n0 + nf * 16 + l15) * CI_ + c + g4 * 8]);
        acc[nf] = mfma16(a, bb, acc[nf]);
      }
    }
    __syncthreads();   // previous iteration's PV reads of lds_p complete
#pragma unroll
    for (int nf = 0; nf < 2; ++nf) {
      u16x4 pk;
#pragma unroll
      for (int r = 0; r < 4; ++r) pk[r] = f2bf(__expf(acc[nf][r] * 0.0625f));
      *reinterpret_cast<u16x4*>(&lds_p[nf * 16 + l15][w * 16 + g4 * 4]) = pk;
    }
    __syncthreads();
    // PV: A = P (rows n, k = m), B = g_s (k = m, cols c); k-map m = 8g+j both sides
#pragma unroll
    for (int mk = 0; mk < 2; ++mk) {
      s16x8 afr[2];
#pragma unroll
      for (int nf = 0; nf < 2; ++nf)
        afr[nf] = *reinterpret_cast<const s16x8*>(&lds_p[nf * 16 + l15][mk * 32 + g4 * 8]);
#pragma unroll
      for (int cf = 0; cf < 4; ++cf) {
        s16x8 bb = *reinterpret_cast<const s16x8*>(
            &gsb[(size_t)(c0 + cf * 16 + l15) * HW_ + it * 64 + mk * 32 + g4 * 8]);
#pragma unroll
        for (int nf = 0; nf < 2; ++nf)
          oacc[nf][cf] = mfma16(afr[nf], bb, oacc[nf][cf]);
      }
    }
  }

#pragma unroll
  for (int nf = 0; nf < 2; ++nf)
#pragma unroll
    for (int r = 0; r < 4; ++r) {
      int n = n0 + nf * 16 + g4 * 4 + r;
      float il = invL[b * HW_ + n];
#pragma unroll
      for (int cf = 0; cf < 4; ++cf)
        y[((size_t)b * HW_ + n) * CI_ + c0 + cf * 16 + l15] = f2bf(oacc[nf][cf][r] * il);
    }
}

// ---------------------------------------------------------------------------
// K4: z = W_w @ y^T + W_b  (per batch, M=512, N=4096, K=256, NT direct-global)
// also per-channel partial sums for BN.
// ---------------------------------------------------------------------------
__global__ __launch_bounds__(256) void k4_wconv(
    const u16* __restrict__ y, const float* __restrict__ Ww, const float* __restrict__ Wb,
    float* __restrict__ z, float* __restrict__ zsum, float* __restrict__ zsq)
{
  const int tid = threadIdx.x;
  const int lane = tid & 63, wid = tid >> 6;
  const int wm = wid >> 1, wn = wid & 1;
  const int l15 = lane & 15, g4 = lane >> 4;
  const int n0 = blockIdx.x * 64, o0 = blockIdx.y * 64, b = blockIdx.z;

  f32x4 acc[2][2] = {};
#pragma unroll
  for (int c = 0; c < CI_; c += 32) {
    s16x8 afr[2], bfr[2];
#pragma unroll
    for (int mf = 0; mf < 2; ++mf) {
      int row = o0 + wm * 32 + mf * 16 + l15;
      const float4* w4 = reinterpret_cast<const float4*>(&Ww[(size_t)row * CI_ + c + g4 * 8]);
      float4 v0 = w4[0], v1 = w4[1];
      s16x8 a;
      a[0] = (short)f2bf(v0.x); a[1] = (short)f2bf(v0.y);
      a[2] = (short)f2bf(v0.z); a[3] = (short)f2bf(v0.w);
      a[4] = (short)f2bf(v1.x); a[5] = (short)f2bf(v1.y);
      a[6] = (short)f2bf(v1.z); a[7] = (short)f2bf(v1.w);
      afr[mf] = a;
    }
#pragma unroll
    for (int nf = 0; nf < 2; ++nf)
      bfr[nf] = *reinterpret_cast<const s16x8*>(
          &y[((size_t)b * HW_ + n0 + wn * 32 + nf * 16 + l15) * CI_ + c + g4 * 8]);
#pragma unroll
    for (int mf = 0; mf < 2; ++mf)
#pragma unroll
      for (int nf = 0; nf < 2; ++nf)
        acc[mf][nf] = mfma16(afr[mf], bfr[nf], acc[mf][nf]);
  }

  __shared__ float lds_ps[2][64][2];
#pragma unroll
  for (int mf = 0; mf < 2; ++mf)
#pragma unroll
    for (int r = 0; r < 4; ++r) {
      int ol = wm * 32 + mf * 16 + g4 * 4 + r;
      int o = o0 + ol;
      float wb = Wb[o];
      float z0 = acc[mf][0][r] + wb, z1 = acc[mf][1][r] + wb;
      size_t zb = ((size_t)b * C_ + o) * HW_ + n0 + wn * 32;
      z[zb + l15] = z0; z[zb + 16 + l15] = z1;
      float s = z0 + z1, q = z0 * z0 + z1 * z1;
      s += __shfl_xor(s, 1); s += __shfl_xor(s, 2); s += __shfl_xor(s, 4); s += __shfl_xor(s, 8);
      q += __shfl_xor(q, 1); q += __shfl_xor(q, 2); q += __shfl_xor(q, 4); q += __shfl_xor(q, 8);
      if (l15 == 0) { lds_ps[wn][ol][0] = s; lds_ps[wn][ol][1] = q; }
    }
  __syncthreads();
  if (tid < 64) {
    float s = lds_ps[0][tid][0] + lds_ps[1][tid][0];
    float q = lds_ps[0][tid][1] + lds_ps[1][tid][1];
    int col = b * 64 + blockIdx.x;
    zsum[(size_t)(o0 + tid) * 256 + col] = s;
    zsq [(size_t)(o0 + tid) * 256 + col] = q;
  }
}

// ---------------------------------------------------------------------------
// K5: BN stats finalize -> per-channel scale/shift
// ---------------------------------------------------------------------------
__global__ void k5_bnstat(const float* __restrict__ zsum, const float* __restrict__ zsq,
                          const float* __restrict__ gamma, const float* __restrict__ beta,
                          float* __restrict__ bns, float* __restrict__ bnb)
{
  int ch = blockIdx.x * 256 + threadIdx.x;
  if (ch >= C_) return;
  float s = 0.f, q = 0.f;
  for (int i = 0; i < 256; ++i) { s += zsum[(size_t)ch * 256 + i]; q += zsq[(size_t)ch * 256 + i]; }
  const float inv_n = 1.0f / (B_ * HW_);
  float mean = s * inv_n;
  float var  = q * inv_n - mean * mean;
  float sc = gamma[ch] * rsqrtf(var + 1e-5f);
  bns[ch] = sc;
  bnb[ch] = beta[ch] - mean * sc;
}

// ---------------------------------------------------------------------------
// K6: out = z*scale[ch] + shift[ch] + x   (in-place on d_out)
// ---------------------------------------------------------------------------
__global__ __launch_bounds__(256) void k6_final(
    const float* __restrict__ x, const float* __restrict__ bns, const float* __restrict__ bnb,
    float* __restrict__ out)
{
  size_t i = ((size_t)blockIdx.x * 256 + threadIdx.x) * 4;
  int ch = (int)((i >> 12) & 511);
  float4 z = *reinterpret_cast<float4*>(&out[i]);
  float4 xv = *reinterpret_cast<const float4*>(&x[i]);
  float sc = bns[ch], sh = bnb[ch];
  float4 o;
  o.x = z.x * sc + sh + xv.x;
  o.y = z.y * sc + sh + xv.y;
  o.z = z.z * sc + sh + xv.z;
  o.w = z.w * sc + sh + xv.w;
  *reinterpret_cast<float4*>(&out[i]) = o;
}

// ---------------------------------------------------------------------------
extern "C" void kernel_launch(void* const* d_in, const int* in_sizes, int n_in,
                              void* d_out, int out_size, void* d_ws, size_t ws_size,
                              hipStream_t stream)
{
  (void)in_sizes; (void)n_in; (void)out_size; (void)ws_size;
  const float* x    = (const float*)d_in[0];
  const float* g_w  = (const float*)d_in[1];
  const float* g_b  = (const float*)d_in[2];
  const float* t_w  = (const float*)d_in[3];
  const float* t_b  = (const float*)d_in[4];
  const float* p_w  = (const float*)d_in[5];
  const float* p_b  = (const float*)d_in[6];
  const float* W_w  = (const float*)d_in[7];
  const float* W_b  = (const float*)d_in[8];
  const float* bng  = (const float*)d_in[9];
  const float* bnb_ = (const float*)d_in[10];

  char* ws = (char*)d_ws;
  const size_t offTheta = 0;
  const size_t offPhi   = (size_t)8  << 20;
  const size_t offG     = (size_t)16 << 20;
  const size_t offY     = (size_t)24 << 20;
  const size_t offLpart = (size_t)32 << 20;
  const size_t offL     = offLpart + 524288;
  const size_t offZsum  = offL + 65536;
  const size_t offZsq   = offZsum + 524288;
  const size_t offBnS   = offZsq + 524288;
  const size_t offBnB   = offBnS + 2048;

  u16*   thetaT = (u16*)(ws + offTheta);
  u16*   phiT   = (u16*)(ws + offPhi);
  u16*   g_s    = (u16*)(ws + offG);
  u16*   y      = (u16*)(ws + offY);
  float* Lpart  = (float*)(ws + offLpart);
  float* invL   = (float*)(ws + offL);
  float* zsum   = (float*)(ws + offZsum);
  float* zsq    = (float*)(ws + offZsq);
  float* bnsV   = (float*)(ws + offBnS);
  float* bnbV   = (float*)(ws + offBnB);
  float* z      = (float*)d_out;

  hipLaunchKernelGGL(k1_proj, dim3(64, 4, 12), dim3(256), 0, stream,
                     x, g_w, g_b, t_w, t_b, p_w, p_b, g_s, thetaT, phiT);
  hipLaunchKernelGGL(k2_lse, dim3(128, 8, 4), dim3(256), 0, stream,
                     thetaT, phiT, Lpart);
  hipLaunchKernelGGL(k2b_lred, dim3(64), dim3(256), 0, stream, Lpart, invL);
  hipLaunchKernelGGL(k3_attn, dim3(128, 4), dim3(256), 0, stream,
                     thetaT, phiT, g_s, invL, y);
  hipLaunchKernelGGL(k4_wconv, dim3(64, 8, 4), dim3(256), 0, stream,
                     y, W_w, W_b, z, zsum, zsq);
  hipLaunchKernelGGL(k5_bnstat, dim3(2), dim3(256), 0, stream,
                     zsum, zsq, bng, bnb_, bnsV, bnbV);
  hipLaunchKernelGGL(k6_final, dim3(8192), dim3(256), 0, stream,
                     x, bnsV, bnbV, z);
}

// Round 2
// 292.312 us; speedup vs baseline: 2.1676x; 2.1676x over previous
//
#include <hip/hip_runtime.h>

typedef unsigned short u16;
typedef __attribute__((ext_vector_type(4))) u16 u16x4;
typedef __attribute__((ext_vector_type(8))) u16 u16x8;
typedef __attribute__((ext_vector_type(8))) short s16x8;   // 8 x bf16 (4 VGPRs)
typedef __attribute__((ext_vector_type(4))) float f32x4;

#define B_  4
#define C_  512
#define CI_ 256
#define HW_ 4096

static __device__ __forceinline__ u16 f2bf(float f) {
  unsigned u = __float_as_uint(f);
  return (u16)((u + 0x7FFFu + ((u >> 16) & 1u)) >> 16);   // RNE
}

static __device__ __forceinline__ f32x4 mfma16(s16x8 a, s16x8 b, f32x4 c) {
  return __builtin_amdgcn_mfma_f32_16x16x32_bf16(a, b, c, 0, 0, 0);
}

typedef __attribute__((address_space(3))) unsigned int as3_u32;
typedef const __attribute__((address_space(1))) unsigned int as1_u32;
static __device__ __forceinline__ void gload16(const u16* g, u16* l) {
  __builtin_amdgcn_global_load_lds((as1_u32*)g, (as3_u32*)l, 16, 0, 0);
}

// ---------------------------------------------------------------------------
// K1: projections.  per (proj p, batch b): out = w(256x512) @ x_b(512x4096) + bias
//   p==0 (g)      -> g_s   (B, Ci, HW)  channel-major
//   p==1 (theta)  -> thetaT(B, HW, Ci)  token-major (transposed store via LDS)
//   p==2 (phi)    -> phiT  (B, HW, Ci)
// ---------------------------------------------------------------------------
__global__ __launch_bounds__(256) void k1_proj(
    const float* __restrict__ x,
    const float* __restrict__ wg, const float* __restrict__ bg,
    const float* __restrict__ wt, const float* __restrict__ bt,
    const float* __restrict__ wp, const float* __restrict__ bp,
    u16* __restrict__ g_s, u16* __restrict__ thetaT, u16* __restrict__ phiT)
{
  const int tid = threadIdx.x;
  const int lane = tid & 63, wid = tid >> 6;
  const int wm = wid >> 1, wn = wid & 1;
  const int l15 = lane & 15, g4 = lane >> 4;
  const int n0 = blockIdx.x * 64;
  const int m0 = blockIdx.y * 64;
  const int p = blockIdx.z >> 2, b = blockIdx.z & 3;
  const float* w    = (p == 0) ? wg : (p == 1) ? wt : wp;
  const float* bias = (p == 0) ? bg : (p == 1) ? bt : bp;
  const float* xb = x + (size_t)b * C_ * HW_;

  __shared__ u16 lds_x[32][76];   // [k][n] bf16, padded
  __shared__ u16 lds_t[64][72];   // epilogue transpose staging

  f32x4 acc[2][2] = {};

  for (int kk = 0; kk < C_; kk += 32) {
    __syncthreads();
#pragma unroll
    for (int i = 0; i < 2; ++i) {
      int idx = tid + i * 256;                  // 0..511 float4s
      int kr = idx >> 4, nc = (idx & 15) << 2;
      float4 v = *reinterpret_cast<const float4*>(&xb[(size_t)(kk + kr) * HW_ + n0 + nc]);
      u16x4 h; h[0] = f2bf(v.x); h[1] = f2bf(v.y); h[2] = f2bf(v.z); h[3] = f2bf(v.w);
      *reinterpret_cast<u16x4*>(&lds_x[kr][nc]) = h;
    }
    __syncthreads();

    s16x8 afr[2], bfr[2];
#pragma unroll
    for (int mf = 0; mf < 2; ++mf) {
      int row = m0 + wm * 32 + mf * 16 + l15;
      const float4* w4 = reinterpret_cast<const float4*>(&w[(size_t)row * C_ + kk + g4 * 8]);
      float4 v0 = w4[0], v1 = w4[1];
      s16x8 a;
      a[0] = (short)f2bf(v0.x); a[1] = (short)f2bf(v0.y);
      a[2] = (short)f2bf(v0.z); a[3] = (short)f2bf(v0.w);
      a[4] = (short)f2bf(v1.x); a[5] = (short)f2bf(v1.y);
      a[6] = (short)f2bf(v1.z); a[7] = (short)f2bf(v1.w);
      afr[mf] = a;
    }
#pragma unroll
    for (int nf = 0; nf < 2; ++nf) {
      int col = wn * 32 + nf * 16 + l15;
      s16x8 bb;
#pragma unroll
      for (int j = 0; j < 8; ++j) bb[j] = (short)lds_x[g4 * 8 + j][col];
      bfr[nf] = bb;
    }
#pragma unroll
    for (int mf = 0; mf < 2; ++mf)
#pragma unroll
      for (int nf = 0; nf < 2; ++nf)
        acc[mf][nf] = mfma16(afr[mf], bfr[nf], acc[mf][nf]);
  }

#pragma unroll
  for (int mf = 0; mf < 2; ++mf)
#pragma unroll
    for (int r = 0; r < 4; ++r) {
      float bv = bias[m0 + wm * 32 + mf * 16 + g4 * 4 + r];
      acc[mf][0][r] += bv; acc[mf][1][r] += bv;
    }

  if (p == 0) {
#pragma unroll
    for (int mf = 0; mf < 2; ++mf)
#pragma unroll
      for (int nf = 0; nf < 2; ++nf)
#pragma unroll
        for (int r = 0; r < 4; ++r) {
          int row = m0 + wm * 32 + mf * 16 + g4 * 4 + r;
          int col = n0 + wn * 32 + nf * 16 + l15;
          g_s[((size_t)b * CI_ + row) * HW_ + col] = f2bf(acc[mf][nf][r]);
        }
  } else {
#pragma unroll
    for (int mf = 0; mf < 2; ++mf)
#pragma unroll
      for (int nf = 0; nf < 2; ++nf)
#pragma unroll
        for (int r = 0; r < 4; ++r)
          lds_t[wm * 32 + mf * 16 + g4 * 4 + r][wn * 32 + nf * 16 + l15] = f2bf(acc[mf][nf][r]);
    __syncthreads();
    u16* outp = (p == 1) ? thetaT : phiT;
    int nl = tid >> 2, cs = (tid & 3) << 4;
    u16x8 v0, v1;
#pragma unroll
    for (int i = 0; i < 8; ++i) { v0[i] = lds_t[cs + i][nl]; v1[i] = lds_t[cs + 8 + i][nl]; }
    size_t dst = ((size_t)b * HW_ + n0 + nl) * CI_ + m0 + cs;
    *reinterpret_cast<u16x8*>(&outp[dst])     = v0;
    *reinterpret_cast<u16x8*>(&outp[dst + 8]) = v1;
  }
}

// ---------------------------------------------------------------------------
// K3: fused single-pass attention.
//  per block: n-tile of 64 rows, one batch.  8 waves (512 thr).
//  Iterate m-tiles of 64: stage phi[m-tile] (64x256) + g[:, m-tile] (256x64)
//  into double-buffered swizzled LDS via global_load_lds; QK^T with
//  register-hoisted theta; exp -> P (LDS, padded) + row-sum L accumulation;
//  PV accumulates unnormalized O.  Epilogue: y = O / L.
//  Dynamic LDS: 2*32KB (phi) + 2*32KB (g) + 9216B (P) + 1280B (L) = 141568 B.
// ---------------------------------------------------------------------------
__global__ __launch_bounds__(512) void k3_fused(
    const u16* __restrict__ thetaT, const u16* __restrict__ phiT,
    const u16* __restrict__ g_s, u16* __restrict__ y)
{
  extern __shared__ u16 smem[];
  u16* phi_l = smem;            // [2][64][256] swizzled chunks
  u16* g_l   = smem + 32768;    // [2][256][64] swizzled chunks
  u16* p_l   = smem + 65536;    // [64][72] padded: row stride 144B
  float* Lp  = (float*)(smem + 70144);   // [4][64]
  float* iL  = Lp + 256;                 // [64]

  const int tid = threadIdx.x;
  const int lane = tid & 63, w = tid >> 6;
  const int l15 = lane & 15, g4 = lane >> 4;

  // XCD-aware mapping: batch b lives on XCD pair {2b,2b+1}; its phi+g (4MB)
  // becomes L2-resident for those XCDs.  Default dispatch: xcd = bid % 8.
  const int bid = blockIdx.x;
  const int xcd = bid & 7, slot = bid >> 3;
  const int b  = xcd >> 1;
  const int n0 = ((xcd & 1) * 32 + slot) * 64;

  const int ms = w >> 1, nh = w & 1;    // QK: wave covers m-slice 16, n-half 32
  const int cq = w >> 1, nh2 = w & 1;   // PV: wave covers c-quarter 64, n-half 32

  const u16* thb = thetaT + (size_t)b * HW_ * CI_;
  const u16* phb = phiT   + (size_t)b * HW_ * CI_;
  const u16* gsb = g_s    + (size_t)b * CI_ * HW_;

  // ---- theta hoist: 32 rows x 256 cols per wave, 64 VGPRs ----
  s16x8 thfr[2][8];
#pragma unroll
  for (int nf = 0; nf < 2; ++nf)
#pragma unroll
    for (int cs = 0; cs < 8; ++cs)
      thfr[nf][cs] = *reinterpret_cast<const s16x8*>(
          &thb[(size_t)(n0 + nh * 32 + nf * 16 + l15) * CI_ + cs * 32 + g4 * 8]);

  // ---- staging address precompute (pre-swizzled global source, linear LDS dest)
  const int prow = tid >> 5, pj = tid & 31;   // phi: 16 rows/issue, 32 chunks of 16B
  const int grow = tid >> 3, gj = tid & 7;    // g: 64 rows/issue, 8 chunks of 16B
  const u16* ph_src = phb + (size_t)prow * CI_ + ((pj ^ (prow & 7)) * 8);
  const u16* g_src  = gsb + (size_t)grow * HW_ + ((gj ^ (grow & 7)) * 8);
  u16* ph_dst = phi_l + prow * 256 + pj * 8;
  u16* g_dst  = g_l   + grow * 64  + gj * 8;

  auto stage = [&](int buf, int mt) {
#pragma unroll
    for (int i = 0; i < 4; ++i) {
      gload16(ph_src + (size_t)(mt + i * 16) * 256, ph_dst + buf * 16384 + i * 4096);
      gload16(g_src + mt + (size_t)i * 64 * HW_,    g_dst  + buf * 16384 + i * 4096);
    }
  };

  f32x4 oacc[2][4] = {};
  float psum[2] = {0.f, 0.f};

  stage(0, 0);
  __syncthreads();   // full drain: buf0 ready

  int cur = 0;
  for (int it = 0; it < 64; ++it) {
    const int mt = it * 64;
    if (it + 1 < 64) stage(cur ^ 1, mt + 64);   // async prefetch, in flight across barriers

    // ---- QK^T: S^T[m = mt+ms*16+{g4*4+r}][n = nh*32+nf*16+l15]
    const u16* phc = phi_l + cur * 16384;
    f32x4 acc[2] = {};
#pragma unroll
    for (int cs = 0; cs < 8; ++cs) {
      s16x8 a = *reinterpret_cast<const s16x8*>(
          &phc[(ms * 16 + l15) * 256 + (((cs * 4 + g4) ^ (l15 & 7)) * 8)]);
      acc[0] = mfma16(a, thfr[0][cs], acc[0]);
      acc[1] = mfma16(a, thfr[1][cs], acc[1]);
    }

    // ---- exp, P store, L accumulation (prev PV reads done: end barrier of it-1)
#pragma unroll
    for (int nf = 0; nf < 2; ++nf) {
      u16x4 pk;
#pragma unroll
      for (int r = 0; r < 4; ++r) {
        float e = __expf(acc[nf][r] * 0.0625f);
        psum[nf] += e;
        pk[r] = f2bf(e);
      }
      *reinterpret_cast<u16x4*>(&p_l[(nh * 32 + nf * 16 + l15) * 72 + ms * 16 + g4 * 4]) = pk;
    }
    // P visibility: drain own LDS ops, barrier — staging vmcnt stays in flight
    asm volatile("s_waitcnt lgkmcnt(0)" ::: "memory");
    __builtin_amdgcn_s_barrier();
    asm volatile("" ::: "memory");

    // ---- PV: O[n = nh2*32+nf*16+{g4*4+r}][c = cq*64+cf*16+l15]
    const u16* gc = g_l + cur * 16384;
#pragma unroll
    for (int mk = 0; mk < 2; ++mk) {
      s16x8 pa[2];
#pragma unroll
      for (int nf = 0; nf < 2; ++nf)
        pa[nf] = *reinterpret_cast<const s16x8*>(
            &p_l[(nh2 * 32 + nf * 16 + l15) * 72 + mk * 32 + g4 * 8]);
#pragma unroll
      for (int cf = 0; cf < 4; ++cf) {
        int crow = cq * 64 + cf * 16 + l15;
        s16x8 bb = *reinterpret_cast<const s16x8*>(
            &gc[crow * 64 + (((mk * 4 + g4) ^ (crow & 7)) * 8)]);
        oacc[0][cf] = mfma16(pa[0], bb, oacc[0][cf]);
        oacc[1][cf] = mfma16(pa[1], bb, oacc[1][cf]);
      }
    }

    // ---- end of iter: staged tile complete, all P/g reads consumed
    asm volatile("s_waitcnt vmcnt(0)" ::: "memory");
    __builtin_amdgcn_s_barrier();
    asm volatile("" ::: "memory");
    cur ^= 1;
  }

  // ---- epilogue: L reduce + normalize + store y (token-major bf16)
#pragma unroll
  for (int nf = 0; nf < 2; ++nf) {
    psum[nf] += __shfl_xor(psum[nf], 16);
    psum[nf] += __shfl_xor(psum[nf], 32);
  }
  if (lane < 16) {
    Lp[ms * 64 + nh * 32 + lane]      = psum[0];
    Lp[ms * 64 + nh * 32 + 16 + lane] = psum[1];
  }
  __syncthreads();
  if (tid < 64) iL[tid] = 1.0f / (Lp[tid] + Lp[64 + tid] + Lp[128 + tid] + Lp[192 + tid]);
  __syncthreads();

  u16* yb = y + ((size_t)b * HW_ + n0) * CI_;
#pragma unroll
  for (int nf = 0; nf < 2; ++nf)
#pragma unroll
    for (int r = 0; r < 4; ++r) {
      int nl = nh2 * 32 + nf * 16 + g4 * 4 + r;
      float il = iL[nl];
#pragma unroll
      for (int cf = 0; cf < 4; ++cf)
        yb[(size_t)nl * CI_ + cq * 64 + cf * 16 + l15] = f2bf(oacc[nf][cf][r] * il);
    }
}

// ---------------------------------------------------------------------------
// K4: z = W_w @ y^T + W_b  (per batch, M=512, N=4096, K=256, NT direct-global)
// also per-channel partial sums for BN.
// ---------------------------------------------------------------------------
__global__ __launch_bounds__(256) void k4_wconv(
    const u16* __restrict__ y, const float* __restrict__ Ww, const float* __restrict__ Wb,
    float* __restrict__ z, float* __restrict__ zsum, float* __restrict__ zsq)
{
  const int tid = threadIdx.x;
  const int lane = tid & 63, wid = tid >> 6;
  const int wm = wid >> 1, wn = wid & 1;
  const int l15 = lane & 15, g4 = lane >> 4;
  const int n0 = blockIdx.x * 64, o0 = blockIdx.y * 64, b = blockIdx.z;

  f32x4 acc[2][2] = {};
#pragma unroll
  for (int c = 0; c < CI_; c += 32) {
    s16x8 afr[2], bfr[2];
#pragma unroll
    for (int mf = 0; mf < 2; ++mf) {
      int row = o0 + wm * 32 + mf * 16 + l15;
      const float4* w4 = reinterpret_cast<const float4*>(&Ww[(size_t)row * CI_ + c + g4 * 8]);
      float4 v0 = w4[0], v1 = w4[1];
      s16x8 a;
      a[0] = (short)f2bf(v0.x); a[1] = (short)f2bf(v0.y);
      a[2] = (short)f2bf(v0.z); a[3] = (short)f2bf(v0.w);
      a[4] = (short)f2bf(v1.x); a[5] = (short)f2bf(v1.y);
      a[6] = (short)f2bf(v1.z); a[7] = (short)f2bf(v1.w);
      afr[mf] = a;
    }
#pragma unroll
    for (int nf = 0; nf < 2; ++nf)
      bfr[nf] = *reinterpret_cast<const s16x8*>(
          &y[((size_t)b * HW_ + n0 + wn * 32 + nf * 16 + l15) * CI_ + c + g4 * 8]);
#pragma unroll
    for (int mf = 0; mf < 2; ++mf)
#pragma unroll
      for (int nf = 0; nf < 2; ++nf)
        acc[mf][nf] = mfma16(afr[mf], bfr[nf], acc[mf][nf]);
  }

  __shared__ float lds_ps[2][64][2];
#pragma unroll
  for (int mf = 0; mf < 2; ++mf)
#pragma unroll
    for (int r = 0; r < 4; ++r) {
      int ol = wm * 32 + mf * 16 + g4 * 4 + r;
      int o = o0 + ol;
      float wb = Wb[o];
      float z0 = acc[mf][0][r] + wb, z1 = acc[mf][1][r] + wb;
      size_t zb = ((size_t)b * C_ + o) * HW_ + n0 + wn * 32;
      z[zb + l15] = z0; z[zb + 16 + l15] = z1;
      float s = z0 + z1, q = z0 * z0 + z1 * z1;
      s += __shfl_xor(s, 1); s += __shfl_xor(s, 2); s += __shfl_xor(s, 4); s += __shfl_xor(s, 8);
      q += __shfl_xor(q, 1); q += __shfl_xor(q, 2); q += __shfl_xor(q, 4); q += __shfl_xor(q, 8);
      if (l15 == 0) { lds_ps[wn][ol][0] = s; lds_ps[wn][ol][1] = q; }
    }
  __syncthreads();
  if (tid < 64) {
    float s = lds_ps[0][tid][0] + lds_ps[1][tid][0];
    float q = lds_ps[0][tid][1] + lds_ps[1][tid][1];
    int col = b * 64 + blockIdx.x;
    zsum[(size_t)(o0 + tid) * 256 + col] = s;
    zsq [(size_t)(o0 + tid) * 256 + col] = q;
  }
}

// ---------------------------------------------------------------------------
// K5: BN stats finalize -> per-channel scale/shift
// ---------------------------------------------------------------------------
__global__ void k5_bnstat(const float* __restrict__ zsum, const float* __restrict__ zsq,
                          const float* __restrict__ gamma, const float* __restrict__ beta,
                          float* __restrict__ bns, float* __restrict__ bnb)
{
  int ch = blockIdx.x * 256 + threadIdx.x;
  if (ch >= C_) return;
  float s = 0.f, q = 0.f;
  for (int i = 0; i < 256; ++i) { s += zsum[(size_t)ch * 256 + i]; q += zsq[(size_t)ch * 256 + i]; }
  const float inv_n = 1.0f / (B_ * HW_);
  float mean = s * inv_n;
  float var  = q * inv_n - mean * mean;
  float sc = gamma[ch] * rsqrtf(var + 1e-5f);
  bns[ch] = sc;
  bnb[ch] = beta[ch] - mean * sc;
}

// ---------------------------------------------------------------------------
// K6: out = z*scale[ch] + shift[ch] + x   (in-place on d_out)
// ---------------------------------------------------------------------------
__global__ __launch_bounds__(256) void k6_final(
    const float* __restrict__ x, const float* __restrict__ bns, const float* __restrict__ bnb,
    float* __restrict__ out)
{
  size_t i = ((size_t)blockIdx.x * 256 + threadIdx.x) * 4;
  int ch = (int)((i >> 12) & 511);
  float4 z = *reinterpret_cast<float4*>(&out[i]);
  float4 xv = *reinterpret_cast<const float4*>(&x[i]);
  float sc = bns[ch], sh = bnb[ch];
  float4 o;
  o.x = z.x * sc + sh + xv.x;
  o.y = z.y * sc + sh + xv.y;
  o.z = z.z * sc + sh + xv.z;
  o.w = z.w * sc + sh + xv.w;
  *reinterpret_cast<float4*>(&out[i]) = o;
}

// ---------------------------------------------------------------------------
extern "C" void kernel_launch(void* const* d_in, const int* in_sizes, int n_in,
                              void* d_out, int out_size, void* d_ws, size_t ws_size,
                              hipStream_t stream)
{
  (void)in_sizes; (void)n_in; (void)out_size; (void)ws_size;
  const float* x    = (const float*)d_in[0];
  const float* g_w  = (const float*)d_in[1];
  const float* g_b  = (const float*)d_in[2];
  const float* t_w  = (const float*)d_in[3];
  const float* t_b  = (const float*)d_in[4];
  const float* p_w  = (const float*)d_in[5];
  const float* p_b  = (const float*)d_in[6];
  const float* W_w  = (const float*)d_in[7];
  const float* W_b  = (const float*)d_in[8];
  const float* bng  = (const float*)d_in[9];
  const float* bnb_ = (const float*)d_in[10];

  char* ws = (char*)d_ws;
  u16*   thetaT = (u16*)(ws + ((size_t)0  << 20));
  u16*   phiT   = (u16*)(ws + ((size_t)8  << 20));
  u16*   g_s    = (u16*)(ws + ((size_t)16 << 20));
  u16*   y      = (u16*)(ws + ((size_t)24 << 20));
  float* zsum   = (float*)(ws + ((size_t)32 << 20));
  float* zsq    = (float*)(ws + ((size_t)32 << 20) + 524288);
  float* bnsV   = (float*)(ws + ((size_t)32 << 20) + 1048576);
  float* bnbV   = (float*)(ws + ((size_t)32 << 20) + 1048576 + 2048);
  float* z      = (float*)d_out;

  const int k3_lds = 141568;
  hipFuncSetAttribute(reinterpret_cast<const void*>(k3_fused),
                      hipFuncAttributeMaxDynamicSharedMemorySize, k3_lds);

  hipLaunchKernelGGL(k1_proj, dim3(64, 4, 12), dim3(256), 0, stream,
                     x, g_w, g_b, t_w, t_b, p_w, p_b, g_s, thetaT, phiT);
  hipLaunchKernelGGL(k3_fused, dim3(256), dim3(512), k3_lds, stream,
                     thetaT, phiT, g_s, y);
  hipLaunchKernelGGL(k4_wconv, dim3(64, 8, 4), dim3(256), 0, stream,
                     y, W_w, W_b, z, zsum, zsq);
  hipLaunchKernelGGL(k5_bnstat, dim3(2), dim3(256), 0, stream,
                     zsum, zsq, bng, bnb_, bnsV, bnbV);
  hipLaunchKernelGGL(k6_final, dim3(8192), dim3(256), 0, stream,
                     x, bnsV, bnbV, z);
}

// Round 4
// 189.506 us; speedup vs baseline: 3.3434x; 1.5425x over previous
//
#include <hip/hip_runtime.h>

typedef unsigned short u16;
typedef __attribute__((ext_vector_type(4))) u16 u16x4;
typedef __attribute__((ext_vector_type(8))) u16 u16x8;
typedef __attribute__((ext_vector_type(8))) short s16x8;   // 8 x bf16 (4 VGPRs)
typedef __attribute__((ext_vector_type(4))) float f32x4;

#define B_  4
#define C_  512
#define CI_ 256
#define HW_ 4096

static __device__ __forceinline__ u16 f2bf(float f) {
  unsigned u = __float_as_uint(f);
  return (u16)((u + 0x7FFFu + ((u >> 16) & 1u)) >> 16);   // RNE
}
static __device__ __forceinline__ float bf2f(u16 h) {
  return __uint_as_float(((unsigned)h) << 16);
}

static __device__ __forceinline__ f32x4 mfma16(s16x8 a, s16x8 b, f32x4 c) {
  return __builtin_amdgcn_mfma_f32_16x16x32_bf16(a, b, c, 0, 0, 0);
}

typedef __attribute__((address_space(3))) unsigned int as3_u32;
typedef const __attribute__((address_space(1))) unsigned int as1_u32;
static __device__ __forceinline__ void gload16(const u16* g, u16* l) {
  __builtin_amdgcn_global_load_lds((as1_u32*)g, (as3_u32*)l, 16, 0, 0);
}

// ---------------------------------------------------------------------------
// K0w: convert weights to bf16.  wB[768][512] = {g_w, theta_w, phi_w};
//      WwB[512][256] = W_w.
// ---------------------------------------------------------------------------
__global__ __launch_bounds__(256) void k0_wcvt(
    const float* __restrict__ wg, const float* __restrict__ wt,
    const float* __restrict__ wp, const float* __restrict__ Ww,
    u16* __restrict__ wB, u16* __restrict__ WwB)
{
  int idx = (blockIdx.x * 256 + threadIdx.x) * 8;   // over 524288 elems
  const float* src;
  u16* dst;
  if (idx < 393216) {
    int r = idx >> 17;                 // 0..2 region of 131072
    src = (r == 0 ? wg : r == 1 ? wt : wp) + (idx & 131071);
    dst = wB + idx;
  } else {
    src = Ww + (idx - 393216);
    dst = WwB + (idx - 393216);
  }
  float4 v0 = *reinterpret_cast<const float4*>(src);
  float4 v1 = *reinterpret_cast<const float4*>(src + 4);
  u16x8 h;
  h[0] = f2bf(v0.x); h[1] = f2bf(v0.y); h[2] = f2bf(v0.z); h[3] = f2bf(v0.w);
  h[4] = f2bf(v1.x); h[5] = f2bf(v1.y); h[6] = f2bf(v1.z); h[7] = f2bf(v1.w);
  *reinterpret_cast<u16x8*>(dst) = h;
}

// ---------------------------------------------------------------------------
// K0x: x (b0+z) (C,HW) f32 -> xT (z,HW,C) bf16 token-major; 64x64 LDS tiles.
//   Processes 2 batches per launch into an 8 MB half-buffer.
// ---------------------------------------------------------------------------
__global__ __launch_bounds__(256) void k0_xt(
    const float* __restrict__ x, u16* __restrict__ xT, int b0)
{
  __shared__ u16 lds[64][72];   // [c][n]
  const int tid = threadIdx.x;
  const int n0 = blockIdx.x * 64, c0 = blockIdx.y * 64;
  const int bl = blockIdx.z;            // 0..1 local
  const int b = b0 + bl;
  const int nc = (tid & 15) * 4;
#pragma unroll
  for (int i = 0; i < 4; ++i) {
    int cr = (tid >> 4) + i * 16;
    float4 v = *reinterpret_cast<const float4*>(
        &x[((size_t)(b * C_ + c0 + cr)) * HW_ + n0 + nc]);
    u16x4 h; h[0] = f2bf(v.x); h[1] = f2bf(v.y); h[2] = f2bf(v.z); h[3] = f2bf(v.w);
    *reinterpret_cast<u16x4*>(&lds[cr][nc]) = h;
  }
  __syncthreads();
  const int n = tid & 63, cg = tid >> 6;
  u16x8 o0, o1;
#pragma unroll
  for (int j = 0; j < 8; ++j) { o0[j] = lds[cg * 16 + j][n]; o1[j] = lds[cg * 16 + 8 + j][n]; }
  size_t dstb = ((size_t)bl * HW_ + n0 + n) * C_ + c0 + cg * 16;
  *reinterpret_cast<u16x8*>(&xT[dstb])     = o0;
  *reinterpret_cast<u16x8*>(&xT[dstb + 8]) = o1;
}

// ---------------------------------------------------------------------------
// K1: fused projections as one staged NT GEMM (per 2-batch half).
//   C[m][n] = sum_k wB[m][k] * xT[n][k],  M=768 (g|theta|phi), K=512
//   tile 128x128, BK=32, 4 waves (2x2), global_load_lds staging, dbuf LDS.
// ---------------------------------------------------------------------------
__global__ __launch_bounds__(256) void k1_proj(
    const u16* __restrict__ wB, const u16* __restrict__ xT,
    const float* __restrict__ bg, const float* __restrict__ bt, const float* __restrict__ bp,
    u16* __restrict__ g_s, u16* __restrict__ thetaT, u16* __restrict__ phiT, int half)
{
  extern __shared__ u16 sm1[];   // dbuf: A0@0 B0@4096 A1@8192 B1@12288 (u16); lds_t overlays
  const int tid = threadIdx.x;
  const int lane = tid & 63, wid = tid >> 6;
  const int wm = wid >> 1, wn = wid & 1;
  const int l15 = lane & 15, g4 = lane >> 4;

  const int bid = blockIdx.x;            // 384 = 12 * 32
  const int r12 = bid % 12;
  const int nt = bid / 12;               // 0..31
  const int mt = r12 >> 1;               // 0..5 (p = mt>>1)
  const int bl = r12 & 1;                // local batch
  const int b = half * 2 + bl;
  const int m0 = mt * 128, n0g = nt * 128;
  const int p = mt >> 1;

  const u16* xb = xT + (size_t)bl * HW_ * C_;

  const int srow = tid >> 2, sch = tid & 3;
  const u16* a_src = wB + (size_t)(m0 + srow) * C_ + sch * 8;
  const u16* b_src = xb + (size_t)(n0g + srow) * C_ + sch * 8;

  f32x4 acc[4][4] = {};

#pragma unroll
  for (int i = 0; i < 2; ++i) {
    gload16(a_src + (size_t)(i * 64) * C_, sm1 + (tid + i * 256) * 8);
    gload16(b_src + (size_t)(i * 64) * C_, sm1 + 4096 + (tid + i * 256) * 8);
  }
  __syncthreads();

  for (int ks = 0; ks < 16; ++ks) {
    const int cur = ks & 1;
    if (ks < 15) {
      const int nk = (ks + 1) * 32;
      u16* dA = sm1 + (cur ^ 1) * 8192;
#pragma unroll
      for (int i = 0; i < 2; ++i) {
        gload16(a_src + (size_t)(i * 64) * C_ + nk, dA + (tid + i * 256) * 8);
        gload16(b_src + (size_t)(i * 64) * C_ + nk, dA + 4096 + (tid + i * 256) * 8);
      }
    }
    const u16* A = sm1 + cur * 8192;
    const u16* Bt = A + 4096;
    s16x8 afr[4], bfr[4];
#pragma unroll
    for (int mf = 0; mf < 4; ++mf)
      afr[mf] = *reinterpret_cast<const s16x8*>(&A[(wm * 64 + mf * 16 + l15) * 32 + g4 * 8]);
#pragma unroll
    for (int nf = 0; nf < 4; ++nf)
      bfr[nf] = *reinterpret_cast<const s16x8*>(&Bt[(wn * 64 + nf * 16 + l15) * 32 + g4 * 8]);
#pragma unroll
    for (int mf = 0; mf < 4; ++mf)
#pragma unroll
      for (int nf = 0; nf < 4; ++nf)
        acc[mf][nf] = mfma16(afr[mf], bfr[nf], acc[mf][nf]);
    __syncthreads();
  }

  const float* bias = (p == 0) ? bg : (p == 1) ? bt : bp;
  const int cib = (mt & 1) * 128;
#pragma unroll
  for (int mf = 0; mf < 4; ++mf)
#pragma unroll
    for (int r = 0; r < 4; ++r) {
      float bv = bias[cib + wm * 64 + mf * 16 + g4 * 4 + r];
#pragma unroll
      for (int nf = 0; nf < 4; ++nf) acc[mf][nf][r] += bv;
    }

  if (p == 0) {
    // g: channel-major store via LDS transpose.  lds_t [128][136] u16
    u16* lds_t = sm1;
#pragma unroll
    for (int mf = 0; mf < 4; ++mf)
#pragma unroll
      for (int nf = 0; nf < 4; ++nf)
#pragma unroll
        for (int r = 0; r < 4; ++r)
          lds_t[(wm * 64 + mf * 16 + g4 * 4 + r) * 136 + wn * 64 + nf * 16 + l15] =
              f2bf(acc[mf][nf][r]);
    __syncthreads();
    const int m = tid >> 1, hh = tid & 1;
    size_t dst = ((size_t)b * CI_ + cib + m) * HW_ + n0g + hh * 64;
#pragma unroll
    for (int j = 0; j < 8; ++j)
      *reinterpret_cast<u16x8*>(&g_s[dst + j * 8]) =
          *reinterpret_cast<const u16x8*>(&lds_t[m * 136 + hh * 64 + j * 8]);
  } else {
    u16* outp = (p == 1) ? thetaT : phiT;
#pragma unroll
    for (int mf = 0; mf < 4; ++mf)
#pragma unroll
      for (int nf = 0; nf < 4; ++nf) {
        u16x4 h;
#pragma unroll
        for (int r = 0; r < 4; ++r) h[r] = f2bf(acc[mf][nf][r]);
        int n = n0g + wn * 64 + nf * 16 + l15;
        *reinterpret_cast<u16x4*>(
            &outp[((size_t)b * HW_ + n) * CI_ + cib + wm * 64 + mf * 16 + g4 * 4]) = h;
      }
  }
}

// ---------------------------------------------------------------------------
// K3: fused single-pass attention, single-barrier counted pipeline.
//  n-tile 64 x batch; 8 waves.  P double-buffered in LDS; phi/g dbuf staged
//  with 1-body prefetch distance.  Body: stage_phi(t+2) ; QK(t+1) ; PV(t) ;
//  drain+barrier ; stage_g(t+2).
// ---------------------------------------------------------------------------
#define OFF_PHI0 0
#define OFF_PHI1 16384
#define OFF_G0   32768
#define OFF_G1   49152
#define OFF_PB0  65536
#define OFF_PB1  70144
#define OFF_LP   74752   // f32 region (u16 offset)

__global__ __launch_bounds__(512) void k3_fused(
    const u16* __restrict__ thetaT, const u16* __restrict__ phiT,
    const u16* __restrict__ g_s, u16* __restrict__ y)
{
  extern __shared__ u16 smem[];
  float* Lp = (float*)(smem + OFF_LP);   // [4][64]
  float* iL = Lp + 256;                  // [64]

  const int tid = threadIdx.x;
  const int lane = tid & 63, w = tid >> 6;
  const int l15 = lane & 15, g4 = lane >> 4;

  const int bid = blockIdx.x;
  const int xcd = bid & 7, slot = bid >> 3;
  const int b  = xcd >> 1;
  const int n0 = ((xcd & 1) * 32 + slot) * 64;

  const int ms = w >> 1, nh = w & 1;    // QK roles
  const int cq = w >> 1, nh2 = w & 1;   // PV roles

  const u16* thb = thetaT + (size_t)b * HW_ * CI_;
  const u16* phb = phiT   + (size_t)b * HW_ * CI_;
  const u16* gsb = g_s    + (size_t)b * CI_ * HW_;

  // theta hoist: 32 rows x 256 k per wave
  s16x8 thfr[2][8];
#pragma unroll
  for (int nf = 0; nf < 2; ++nf)
#pragma unroll
    for (int cs = 0; cs < 8; ++cs)
      thfr[nf][cs] = *reinterpret_cast<const s16x8*>(
          &thb[(size_t)(n0 + nh * 32 + nf * 16 + l15) * CI_ + cs * 32 + g4 * 8]);

  // staging maps (pre-swizzled global source, linear LDS dest)
  const int prow = tid >> 5, pj = tid & 31;
  const int grow = tid >> 3, gj = tid & 7;
  const u16* ph_src = phb + (size_t)prow * CI_ + ((pj ^ (prow & 7)) * 8);
  const u16* g_src  = gsb + (size_t)grow * HW_ + ((gj ^ (grow & 7)) * 8);
  const int ph_do = prow * 256 + pj * 8;
  const int g_do  = grow * 64  + gj * 8;

  auto stage_phi = [&](int off, int mt) {
#pragma unroll
    for (int i = 0; i < 4; ++i)
      gload16(ph_src + (size_t)(mt + i * 16) * CI_, smem + off + ph_do + i * 4096);
  };
  auto stage_g = [&](int off, int mt) {
#pragma unroll
    for (int i = 0; i < 4; ++i)
      gload16(g_src + mt + (size_t)i * 64 * HW_, smem + off + g_do + i * 4096);
  };

  f32x4 oacc[2][4] = {};
  float psum[2] = {0.f, 0.f};

  auto qk_phase = [&](const u16* phN, u16* pbN) {
    f32x4 acc[2] = {};
    __builtin_amdgcn_s_setprio(1);
#pragma unroll
    for (int cs = 0; cs < 8; ++cs) {
      s16x8 a = *reinterpret_cast<const s16x8*>(
          &phN[(ms * 16 + l15) * 256 + (((cs * 4 + g4) ^ (l15 & 7)) * 8)]);
      acc[0] = mfma16(a, thfr[0][cs], acc[0]);
      acc[1] = mfma16(a, thfr[1][cs], acc[1]);
    }
    __builtin_amdgcn_s_setprio(0);
#pragma unroll
    for (int nf = 0; nf < 2; ++nf) {
      u16x4 pk;
#pragma unroll
      for (int r = 0; r < 4; ++r) {
        float e = __expf(acc[nf][r] * 0.0625f);
        psum[nf] += e;
        pk[r] = f2bf(e);
      }
      *reinterpret_cast<u16x4*>(&pbN[(nh * 32 + nf * 16 + l15) * 72 + ms * 16 + g4 * 4]) = pk;
    }
  };
  auto pv_phase = [&](const u16* pbC, const u16* gC) {
    __builtin_amdgcn_s_setprio(1);
#pragma unroll
    for (int mk = 0; mk < 2; ++mk) {
      s16x8 pa[2];
#pragma unroll
      for (int nf = 0; nf < 2; ++nf)
        pa[nf] = *reinterpret_cast<const s16x8*>(
            &pbC[(nh2 * 32 + nf * 16 + l15) * 72 + mk * 32 + g4 * 8]);
#pragma unroll
      for (int cf = 0; cf < 4; ++cf) {
        int crow = cq * 64 + cf * 16 + l15;
        s16x8 bb = *reinterpret_cast<const s16x8*>(
            &gC[crow * 64 + (((mk * 4 + g4) ^ (crow & 7)) * 8)]);
        oacc[0][cf] = mfma16(pa[0], bb, oacc[0][cf]);
        oacc[1][cf] = mfma16(pa[1], bb, oacc[1][cf]);
      }
    }
    __builtin_amdgcn_s_setprio(0);
  };

  // prologue: tiles 0,1 staged; QK(0)
  stage_phi(OFF_PHI0, 0); stage_g(OFF_G0, 0);
  stage_phi(OFF_PHI1, 64); stage_g(OFF_G1, 64);
  asm volatile("s_waitcnt vmcnt(0)" ::: "memory");   // tiles 0,1 landed
  __builtin_amdgcn_s_barrier();
  qk_phase(smem + OFF_PHI0, smem + OFF_PB0);
  asm volatile("s_waitcnt vmcnt(0) lgkmcnt(0)" ::: "memory");  // pb0 visible
  __builtin_amdgcn_s_barrier();

#pragma unroll 1
  for (int it = 0; it < 63; ++it) {
    const int cur = it & 1;
    if (it < 62) stage_phi(cur ? OFF_PHI1 : OFF_PHI0, (it + 2) * 64);
    qk_phase(smem + (cur ? OFF_PHI0 : OFF_PHI1),   // phi[nxt] = tile it+1
             smem + (cur ? OFF_PB0 : OFF_PB1));    // pb[nxt]
    pv_phase(smem + (cur ? OFF_PB1 : OFF_PB0),     // pb[cur] = tile it
             smem + (cur ? OFF_G1 : OFF_G0));      // g[cur]
    asm volatile("s_waitcnt vmcnt(0) lgkmcnt(0)" ::: "memory");
    __builtin_amdgcn_s_barrier();
    if (it < 62) stage_g(cur ? OFF_G1 : OFF_G0, (it + 2) * 64);
  }
  // tail: PV(63)
  pv_phase(smem + OFF_PB1, smem + OFF_G1);

  // epilogue: L reduce + normalize + store
#pragma unroll
  for (int nf = 0; nf < 2; ++nf) {
    psum[nf] += __shfl_xor(psum[nf], 16);
    psum[nf] += __shfl_xor(psum[nf], 32);
  }
  if (lane < 16) {
    Lp[ms * 64 + nh * 32 + lane]      = psum[0];
    Lp[ms * 64 + nh * 32 + 16 + lane] = psum[1];
  }
  __syncthreads();
  if (tid < 64) iL[tid] = 1.0f / (Lp[tid] + Lp[64 + tid] + Lp[128 + tid] + Lp[192 + tid]);
  __syncthreads();

  u16* yb = y + ((size_t)b * HW_ + n0) * CI_;
#pragma unroll
  for (int nf = 0; nf < 2; ++nf)
#pragma unroll
    for (int r = 0; r < 4; ++r) {
      int nl = nh2 * 32 + nf * 16 + g4 * 4 + r;
      float il = iL[nl];
#pragma unroll
      for (int cf = 0; cf < 4; ++cf)
        yb[(size_t)nl * CI_ + cq * 64 + cf * 16 + l15] = f2bf(oacc[nf][cf][r] * il);
    }
}

// ---------------------------------------------------------------------------
// K4: z = W_w @ y^T + W_b, staged GEMM (M=512, N=16384, K=256).
//   z stored bf16 channel-major via LDS transpose; BN partials from f32 accs.
// ---------------------------------------------------------------------------
__global__ __launch_bounds__(256) void k4_wconv(
    const u16* __restrict__ WwB, const u16* __restrict__ y, const float* __restrict__ Wb,
    u16* __restrict__ z, float* __restrict__ zsum, float* __restrict__ zsq)
{
  extern __shared__ u16 sm4[];
  __shared__ float lds_ps[2][128][2];
  const int tid = threadIdx.x;
  const int lane = tid & 63, wid = tid >> 6;
  const int wm = wid >> 1, wn = wid & 1;
  const int l15 = lane & 15, g4 = lane >> 4;

  const int bid = blockIdx.x;            // 512 = 8 xcd * 64
  const int xcd = bid & 7, slot = bid >> 3;
  const int b = xcd >> 1, half = xcd & 1;
  const int mt = slot & 3;
  const int nt = half * 16 + (slot >> 2);
  const int o0 = mt * 128, n0g = nt * 128;

  const int srow = tid >> 2, sch = tid & 3;
  const u16* a_src = WwB + (size_t)(o0 + srow) * CI_ + sch * 8;
  const u16* b_src = y + ((size_t)(b * HW_ + n0g + srow)) * CI_ + sch * 8;

  f32x4 acc[4][4] = {};

#pragma unroll
  for (int i = 0; i < 2; ++i) {
    gload16(a_src + (size_t)(i * 64) * CI_, sm4 + (tid + i * 256) * 8);
    gload16(b_src + (size_t)(i * 64) * CI_, sm4 + 4096 + (tid + i * 256) * 8);
  }
  __syncthreads();

  for (int ks = 0; ks < 8; ++ks) {
    const int cur = ks & 1;
    if (ks < 7) {
      const int nk = (ks + 1) * 32;
      u16* dA = sm4 + (cur ^ 1) * 8192;
#pragma unroll
      for (int i = 0; i < 2; ++i) {
        gload16(a_src + (size_t)(i * 64) * CI_ + nk, dA + (tid + i * 256) * 8);
        gload16(b_src + (size_t)(i * 64) * CI_ + nk, dA + 4096 + (tid + i * 256) * 8);
      }
    }
    const u16* A = sm4 + cur * 8192;
    const u16* Bt = A + 4096;
    s16x8 afr[4], bfr[4];
#pragma unroll
    for (int mf = 0; mf < 4; ++mf)
      afr[mf] = *reinterpret_cast<const s16x8*>(&A[(wm * 64 + mf * 16 + l15) * 32 + g4 * 8]);
#pragma unroll
    for (int nf = 0; nf < 4; ++nf)
      bfr[nf] = *reinterpret_cast<const s16x8*>(&Bt[(wn * 64 + nf * 16 + l15) * 32 + g4 * 8]);
#pragma unroll
    for (int mf = 0; mf < 4; ++mf)
#pragma unroll
      for (int nf = 0; nf < 4; ++nf)
        acc[mf][nf] = mfma16(afr[mf], bfr[nf], acc[mf][nf]);
    __syncthreads();
  }

  // bias + BN partials + bf16 transpose store
  u16* lds_t = sm4;
#pragma unroll
  for (int mf = 0; mf < 4; ++mf)
#pragma unroll
    for (int r = 0; r < 4; ++r) {
      const int ol = wm * 64 + mf * 16 + g4 * 4 + r;
      float wb = Wb[o0 + ol];
      float s = 0.f, q = 0.f;
#pragma unroll
      for (int nf = 0; nf < 4; ++nf) {
        float zv = acc[mf][nf][r] + wb;
        s += zv; q += zv * zv;
        lds_t[ol * 136 + wn * 64 + nf * 16 + l15] = f2bf(zv);
      }
      s += __shfl_xor(s, 1); s += __shfl_xor(s, 2); s += __shfl_xor(s, 4); s += __shfl_xor(s, 8);
      q += __shfl_xor(q, 1); q += __shfl_xor(q, 2); q += __shfl_xor(q, 4); q += __shfl_xor(q, 8);
      if (l15 == 0) { lds_ps[wn][ol][0] = s; lds_ps[wn][ol][1] = q; }
    }
  __syncthreads();
  {
    const int m = tid >> 1, hh = tid & 1;
    size_t dst = ((size_t)(b * C_ + o0 + m)) * HW_ + n0g + hh * 64;
#pragma unroll
    for (int j = 0; j < 8; ++j)
      *reinterpret_cast<u16x8*>(&z[dst + j * 8]) =
          *reinterpret_cast<const u16x8*>(&lds_t[m * 136 + hh * 64 + j * 8]);
  }
  if (tid < 128) {
    int col = b * 32 + nt;
    zsum[(size_t)(o0 + tid) * 128 + col] = lds_ps[0][tid][0] + lds_ps[1][tid][0];
    zsq [(size_t)(o0 + tid) * 128 + col] = lds_ps[0][tid][1] + lds_ps[1][tid][1];
  }
}

// ---------------------------------------------------------------------------
// K5: BN stats finalize
// ---------------------------------------------------------------------------
__global__ void k5_bnstat(const float* __restrict__ zsum, const float* __restrict__ zsq,
                          const float* __restrict__ gamma, const float* __restrict__ beta,
                          float* __restrict__ bns, float* __restrict__ bnb)
{
  int ch = blockIdx.x * 256 + threadIdx.x;
  if (ch >= C_) return;
  float s = 0.f, q = 0.f;
  for (int i = 0; i < 128; ++i) { s += zsum[(size_t)ch * 128 + i]; q += zsq[(size_t)ch * 128 + i]; }
  const float inv_n = 1.0f / (B_ * HW_);
  float mean = s * inv_n;
  float var  = q * inv_n - mean * mean;
  float sc = gamma[ch] * rsqrtf(var + 1e-5f);
  bns[ch] = sc;
  bnb[ch] = beta[ch] - mean * sc;
}

// ---------------------------------------------------------------------------
// K6: out = z_bf16*scale[ch] + shift[ch] + x   (8 elems/thread, 4096 blocks)
// ---------------------------------------------------------------------------
__global__ __launch_bounds__(256) void k6_final(
    const u16* __restrict__ z, const float* __restrict__ x,
    const float* __restrict__ bns, const float* __restrict__ bnb,
    float* __restrict__ out)
{
  size_t i = ((size_t)blockIdx.x * 256 + threadIdx.x) * 8;
  int ch = (int)((i >> 12) & 511);
  float sc = bns[ch], sh = bnb[ch];
  u16x8 zv = *reinterpret_cast<const u16x8*>(&z[i]);
  float4 x0 = *reinterpret_cast<const float4*>(&x[i]);
  float4 x1 = *reinterpret_cast<const float4*>(&x[i + 4]);
  float4 o0, o1;
  o0.x = bf2f(zv[0]) * sc + sh + x0.x;
  o0.y = bf2f(zv[1]) * sc + sh + x0.y;
  o0.z = bf2f(zv[2]) * sc + sh + x0.z;
  o0.w = bf2f(zv[3]) * sc + sh + x0.w;
  o1.x = bf2f(zv[4]) * sc + sh + x1.x;
  o1.y = bf2f(zv[5]) * sc + sh + x1.y;
  o1.z = bf2f(zv[6]) * sc + sh + x1.z;
  o1.w = bf2f(zv[7]) * sc + sh + x1.w;
  *reinterpret_cast<float4*>(&out[i])     = o0;
  *reinterpret_cast<float4*>(&out[i + 4]) = o1;
}

// ---------------------------------------------------------------------------
// Workspace layout (peak 33.6 MB, under proven-safe 35.2 MB):
//   [0,8M):   xT half-buffer (k0x->k1), then y (k3->k4)
//   [8M,16M): thetaT (k1->k3), then zbf low half (k4->k6)
//   [16M,24M):phiT  (k1->k3), then zbf high half
//   [24M,32M):g_s   (k1->k3), then zsum/zsq/bns/bnb (k4->k6)
//   [32M,~33.6M): wB, WwB
// ---------------------------------------------------------------------------
extern "C" void kernel_launch(void* const* d_in, const int* in_sizes, int n_in,
                              void* d_out, int out_size, void* d_ws, size_t ws_size,
                              hipStream_t stream)
{
  (void)in_sizes; (void)n_in; (void)out_size; (void)ws_size;
  const float* x    = (const float*)d_in[0];
  const float* g_w  = (const float*)d_in[1];
  const float* g_b  = (const float*)d_in[2];
  const float* t_w  = (const float*)d_in[3];
  const float* t_b  = (const float*)d_in[4];
  const float* p_w  = (const float*)d_in[5];
  const float* p_b  = (const float*)d_in[6];
  const float* W_w  = (const float*)d_in[7];
  const float* W_b  = (const float*)d_in[8];
  const float* bng  = (const float*)d_in[9];
  const float* bnb_ = (const float*)d_in[10];

  char* ws = (char*)d_ws;
  const size_t M8 = (size_t)8 << 20;
  u16*   xT     = (u16*)(ws + 0);          // 8 MB (per-half)
  u16*   y      = (u16*)(ws + 0);          // overlays xT after k1
  u16*   thetaT = (u16*)(ws + M8);         // 8 MB
  u16*   phiT   = (u16*)(ws + 2 * M8);     // 8 MB
  u16*   g_s    = (u16*)(ws + 3 * M8);     // 8 MB
  u16*   zbf    = (u16*)(ws + M8);         // 16 MB, overlays theta+phi after k3
  float* zsum   = (float*)(ws + 3 * M8);   // overlays g_s after k3
  float* zsq    = (float*)(ws + 3 * M8 + 262144);
  float* bnsV   = (float*)(ws + 3 * M8 + 524288);
  float* bnbV   = (float*)(ws + 3 * M8 + 526336);
  u16*   wB     = (u16*)(ws + 4 * M8);     // 768 KB
  u16*   WwB    = (u16*)(ws + 4 * M8 + 786432);  // 256 KB
  float* out    = (float*)d_out;

  const int k1_lds = 34816;
  const int k3_lds = 150784;
  const int k4_lds = 34816;
  hipFuncSetAttribute(reinterpret_cast<const void*>(k1_proj),
                      hipFuncAttributeMaxDynamicSharedMemorySize, k1_lds);
  hipFuncSetAttribute(reinterpret_cast<const void*>(k3_fused),
                      hipFuncAttributeMaxDynamicSharedMemorySize, k3_lds);
  hipFuncSetAttribute(reinterpret_cast<const void*>(k4_wconv),
                      hipFuncAttributeMaxDynamicSharedMemorySize, k4_lds);

  hipLaunchKernelGGL(k0_wcvt, dim3(256), dim3(256), 0, stream,
                     g_w, t_w, p_w, W_w, wB, WwB);
  for (int half = 0; half < 2; ++half) {
    hipLaunchKernelGGL(k0_xt, dim3(64, 8, 2), dim3(256), 0, stream, x, xT, half * 2);
    hipLaunchKernelGGL(k1_proj, dim3(384), dim3(256), k1_lds, stream,
                       wB, xT, g_b, t_b, p_b, g_s, thetaT, phiT, half);
  }
  hipLaunchKernelGGL(k3_fused, dim3(256), dim3(512), k3_lds, stream,
                     thetaT, phiT, g_s, y);
  hipLaunchKernelGGL(k4_wconv, dim3(512), dim3(256), k4_lds, stream,
                     WwB, y, W_b, zbf, zsum, zsq);
  hipLaunchKernelGGL(k5_bnstat, dim3(2), dim3(256), 0, stream,
                     zsum, zsq, bng, bnb_, bnsV, bnbV);
  hipLaunchKernelGGL(k6_final, dim3(4096), dim3(256), 0, stream,
                     zbf, x, bnsV, bnbV, out);
}